// Round 10
// baseline (196.616 us; speedup 1.0000x reference)
//
#include <hip/hip_runtime.h>
#include <stdint.h>

typedef _Float16 f16;
typedef __attribute__((ext_vector_type(4))) _Float16 f16x4;
typedef __attribute__((ext_vector_type(8))) _Float16 f16x8;
typedef __attribute__((ext_vector_type(4))) float f32x4;
typedef __attribute__((ext_vector_type(16))) float f32x16;
typedef __attribute__((ext_vector_type(4))) int int4v;

#define TT 2048
#define HH 8

static __device__ __forceinline__ void gload_lds16(const void* g, void* l) {
  __builtin_amdgcn_global_load_lds((const __attribute__((address_space(1))) void*)g,
                                   (__attribute__((address_space(3))) void*)l, 16, 0, 0);
}

static __device__ __forceinline__ int pkf16(float a, float b) {
  auto h = __builtin_amdgcn_cvt_pkrtz(a, b);  // __fp16 ext_vector(2)
  return __builtin_bit_cast(int, h);
}

static __device__ __forceinline__ void plswap(int& a, int& b) {
  asm("v_permlane32_swap_b32 %0, %1" : "+v"(a), "+v"(b));
}

// Build PV A-fragment (rows=q=lane&31, k-slots=(lane>>5)*8+j) from swapped-QK
// D regs p0..p7 (k = (r&3)+8*(r>>2)+4*hi within a 16-k block).
static __device__ __forceinline__ f16x8 mkpa(float p0, float p1, float p2, float p3,
                                             float p4, float p5, float p6, float p7) {
  int a0 = pkf16(p0, p1), a1 = pkf16(p2, p3);
  int b0 = pkf16(p4, p5), b1 = pkf16(p6, p7);
  plswap(a0, b0);
  plswap(a1, b1);
  int4v w = {a0, a1, b0, b1};
  return __builtin_bit_cast(f16x8, w);
}

// ---------------- merged prep: cvt q/k/v, cvt weights, mask count ----------
__global__ __launch_bounds__(256) void prep(
    const float* __restrict__ q, const float* __restrict__ k,
    const float* __restrict__ v, const float* __restrict__ Wq,
    const float* __restrict__ Wk, const float* __restrict__ Wv,
    const float* __restrict__ Wo, const int* __restrict__ mask,
    f16* __restrict__ qkv16, f16* __restrict__ w16, float* __restrict__ cnt) {
  const int bid = blockIdx.x;
  if (bid < 12288) {
    int g = bid * 256 + threadIdx.x;
    int sel = g >> 20, off = g & 1048575;
    const float* s = sel == 0 ? q : sel == 1 ? k : v;
    float4 val = ((const float4*)s)[off];
    f16x4 o = {(_Float16)val.x, (_Float16)val.y, (_Float16)val.z, (_Float16)val.w};
    ((f16x4*)qkv16)[g] = o;
  } else if (bid < 13312) {
    int g = (bid - 12288) * 256 + threadIdx.x;
    int sel = g >> 16, off = g & 65535;
    const float* s = sel == 0 ? Wq : sel == 1 ? Wk : (sel == 2 ? Wv : Wo);
    float4 val = ((const float4*)s)[off];
    f16x4 o = {(_Float16)val.x, (_Float16)val.y, (_Float16)val.z, (_Float16)val.w};
    ((f16x4*)w16)[g] = o;
  } else {
    __shared__ int red[256];
    int b = bid - 13312, t = threadIdx.x;
    int s = 0;
#pragma unroll
    for (int i = 0; i < 8; ++i) s += (mask[b * 2048 + t * 8 + i] == 0) ? 1 : 0;
    red[t] = s;
    __syncthreads();
    for (int off = 128; off > 0; off >>= 1) {
      if (t < off) red[t] += red[t + off];
      __syncthreads();
    }
    if (t == 0) cnt[b] = (float)red[0];
  }
}

// ---------------- merged q/k/v projection GEMM, 64x128 tiles --------------
__global__ __launch_bounds__(128, 3) void gemm_qkv(
    const f16* __restrict__ q16, const f16* __restrict__ k16,
    const f16* __restrict__ v16, const f16* __restrict__ wq,
    const f16* __restrict__ wk, const f16* __restrict__ wv,
    const float* __restrict__ bq, const float* __restrict__ bk,
    const float* __restrict__ bv, const int* __restrict__ mask,
    f16* __restrict__ qhp, f16* __restrict__ khp, f16* __restrict__ vhT,
    float scale) {
  __shared__ __align__(16) char SMEM[24576];
  f16* Alds = (f16*)SMEM;              // 64x64 f16 = 8 KB
  f16* Blds = (f16*)(SMEM + 8192);     // 128x64 f16 = 16 KB

  const int raw = blockIdx.x;
  const int bid = (raw & 7) * 192 + (raw >> 3);
  const int prob = bid / 512;
  const int sub = bid - prob * 512;
  const int mt = sub >> 2, nt = sub & 3;

  const f16* A = prob == 0 ? q16 : (prob == 1 ? k16 : v16);
  const f16* W = prob == 0 ? wq : (prob == 1 ? wk : wv);
  const float* bias = prob == 0 ? bq : (prob == 1 ? bk : bv);

  const int tid = threadIdx.x;
  const int w = tid >> 6, lane = tid & 63;
  const int l15 = lane & 15, lg = lane >> 4;

  f32x4 acc[2][8];
#pragma unroll
  for (int mi = 0; mi < 2; ++mi)
#pragma unroll
    for (int nj = 0; nj < 8; ++nj) acc[mi][nj] = {};

  for (int kt = 0; kt < 8; ++kt) {
#pragma unroll
    for (int i = 0; i < 4; ++i) {
      int g = i * 128 + tid;
      int row = g >> 3, jj = g & 7;
      int kb = kt * 128 + ((jj ^ (row & 7)) << 4);
      gload_lds16((const char*)A + (size_t)(mt * 64 + row) * 1024 + kb,
                  (char*)Alds + g * 16);
    }
#pragma unroll
    for (int i = 0; i < 8; ++i) {
      int g = i * 128 + tid;
      int row = g >> 3, jj = g & 7;
      int kb = kt * 128 + ((jj ^ (row & 7)) << 4);
      gload_lds16((const char*)W + (size_t)(nt * 128 + row) * 1024 + kb,
                  (char*)Blds + g * 16);
    }
    __syncthreads();

#pragma unroll
    for (int h2 = 0; h2 < 2; ++h2) {
      f16x8 af[2], bf[8];
#pragma unroll
      for (int mi = 0; mi < 2; ++mi) {
        int row = w * 32 + mi * 16 + l15;
        int bo = (h2 * 64 + (lg << 4)) ^ ((row & 7) << 4);
        af[mi] = *(const f16x8*)((const char*)Alds + row * 128 + bo);
      }
#pragma unroll
      for (int nj = 0; nj < 8; ++nj) {
        int row = nj * 16 + l15;
        int bo = (h2 * 64 + (lg << 4)) ^ ((row & 7) << 4);
        bf[nj] = *(const f16x8*)((const char*)Blds + row * 128 + bo);
      }
#pragma unroll
      for (int mi = 0; mi < 2; ++mi)
#pragma unroll
        for (int nj = 0; nj < 8; ++nj)
          acc[mi][nj] = __builtin_amdgcn_mfma_f32_16x16x32_f16(
              af[mi], bf[nj], acc[mi][nj], 0, 0, 0);
    }
    __syncthreads();
  }

  const int base_m = mt * 64 + w * 32;
  const int base_n = nt * 128;
  float bb[8];
#pragma unroll
  for (int nj = 0; nj < 8; ++nj) bb[nj] = bias[base_n + nj * 16 + l15];

  if (prob != 2) {
    f16* outp = (prob == 0) ? qhp : khp;
#pragma unroll
    for (int mi = 0; mi < 2; ++mi) {
#pragma unroll
      for (int r = 0; r < 4; ++r) {
        int m = base_m + mi * 16 + (lg << 2) + r;
        int b = m >> 11, t = m & (TT - 1);
        float sc = (prob == 0) ? scale : (mask[(b << 11) + t] ? 1.f : 0.f);
#pragma unroll
        for (int nj = 0; nj < 8; ++nj) {
          int n = base_n + nj * 16 + l15;
          int h = n >> 6, c = n & 63;
          float val = (acc[mi][nj][r] + bb[nj]) * sc;
          outp[(((size_t)(b * HH + h) * TT + t) << 6) + c] = (f16)val;
        }
      }
    }
  } else {
    // ---- LDS-transpose epilogue: acc (t x n) -> vhT (B,H,64,T) ----
    __syncthreads();
    f16* T = (f16*)SMEM;
    const int b = base_m >> 11;
    const int t_base = base_m & (TT - 1);
#pragma unroll
    for (int mi = 0; mi < 2; ++mi) {
      float sc_r[4];
#pragma unroll
      for (int r = 0; r < 4; ++r) {
        int t = (t_base + mi * 16 + (lg << 2) + r) & (TT - 1);
        sc_r[r] = mask[(b << 11) + t] ? 1.f : 0.f;
      }
#pragma unroll
      for (int nj = 0; nj < 8; ++nj) {
        f16x4 pk;
#pragma unroll
        for (int r = 0; r < 4; ++r)
          pk[r] = (f16)((acc[mi][nj][r] + bb[nj]) * sc_r[r]);
        *(f16x4*)(&T[(nj * 16 + l15) * 72 + w * 32 + mi * 16 + (lg << 2)]) = pk;
      }
    }
    __syncthreads();
    const int tb = (mt & 31) * 64;
#pragma unroll
    for (int i = 0; i < 8; ++i) {
      int n = (tid >> 3) + i * 16;
      int head = (base_n + n) >> 6, c = (base_n + n) & 63;
      f16x8 val = *(const f16x8*)(&T[n * 72 + (tid & 7) * 8]);
      *(f16x8*)(vhT + ((size_t)(b * HH + head) * 64 + c) * TT + tb +
                (tid & 7) * 8) = val;
    }
  }
}

// ---------------- flash attention: depth-4 counted-vmcnt pipeline ----------
// 4 waves/block: (qg, hf). KBLK=32. Per half: 4 K-bufs + 4 V-bufs (4KB each).
// Steady state: 16 loads in flight; wait vmcnt(12) -> oldest tile staged.
// lgkmcnt(0)+s_barrier before overwriting a buffer (cross-wave safety).
__global__ __launch_bounds__(256, 2) void attn_k(
    const f16* __restrict__ qh, const f16* __restrict__ kh,
    const f16* __restrict__ vhT, const float* __restrict__ cnt,
    f16* __restrict__ att) {
  __shared__ __align__(16) char SMEM[65536];

  const int bid = blockIdx.x;
  const int xcd = bid & 7, jj_ = bid >> 3;
  const int bh = xcd * 4 + (jj_ >> 5);  // 4 bh per XCD
  const int qt = jj_ & 31;
  const int b = bh >> 3, hd = bh & 7;
  const char* Kp = (const char*)(kh + (size_t)bh * (TT * 64));
  const char* Vp = (const char*)(vhT + (size_t)bh * (64 * TT));
  const f16* Q = qh + (size_t)bh * (TT * 64);

  const int tid = threadIdx.x;
  const int w = tid >> 6, lane = tid & 63;
  const int l31 = lane & 31, hi = lane >> 5;
  const int qg = w & 1, hf = w >> 1;
  const int ht = tid & 127;

  const int qrow = qt * 64 + qg * 32 + l31;
  f16x8 qf[4];
#pragma unroll
  for (int c = 0; c < 4; ++c)
    qf[c] = *(const f16x8*)(Q + (size_t)qrow * 64 + c * 16 + hi * 8);

  const f16x8 onesf = {(_Float16)1, (_Float16)1, (_Float16)1, (_Float16)1,
                       (_Float16)1, (_Float16)1, (_Float16)1, (_Float16)1};

  // ---- loop-invariant offsets (all int, LDS accesses stay SMEM+off) ----
  const int kbi = hf * 16384;           // K region base for this half
  const int vbi = 32768 + hf * 16384;   // V region base
  const int g0 = ht, g1 = 128 + ht;
  const int d0 = g0 * 16, d1 = g1 * 16;  // LDS dest offsets within a buffer
  const int rK0 = g0 >> 3, jK0 = g0 & 7, rK1 = g1 >> 3, jK1 = g1 & 7;
  const int rV0 = g0 >> 2, jV0 = g0 & 3, rV1 = g1 >> 2, jV1 = g1 & 3;
  const char* kp0 = Kp + (size_t)(hf * 32) * 4096 + rK0 * 128 + ((jK0 ^ (rK0 & 7)) << 4);
  const char* kp1 = Kp + (size_t)(hf * 32) * 4096 + rK1 * 128 + ((jK1 ^ (rK1 & 7)) << 4);
  const char* vp0 = Vp + (size_t)(hf * 32) * 64 + (size_t)rV0 * 4096 + ((jV0 ^ ((rV0 >> 1) & 3)) << 4);
  const char* vp1 = Vp + (size_t)(hf * 32) * 64 + (size_t)rV1 * 4096 + ((jV1 ^ ((rV1 >> 1) & 3)) << 4);

  // LDS read offsets within a buffer
  const int krA = l31 * 128 + (((0 + hi) ^ (l31 & 7)) << 4);
  const int krB = l31 * 128 + (((2 + hi) ^ (l31 & 7)) << 4);
  const int krC = l31 * 128 + (((4 + hi) ^ (l31 & 7)) << 4);
  const int krD = l31 * 128 + (((6 + hi) ^ (l31 & 7)) << 4);
  const int sw0 = (l31 >> 1) & 3;
  const int vA = l31 * 64 + (((0 + hi) ^ sw0) << 4);
  const int vB = l31 * 64 + (((2 + hi) ^ sw0) << 4);
  const int vC = (32 + l31) * 64 + (((0 + hi) ^ sw0) << 4);
  const int vD = (32 + l31) * 64 + (((2 + hi) ^ sw0) << 4);

  f32x16 o0 = {}, o1 = {}, lD = {};

#define PREF(BUF)                                                   \
  {                                                                 \
    gload_lds16(kp0, SMEM + kbi + 4096 * (BUF) + d0);               \
    gload_lds16(kp1, SMEM + kbi + 4096 * (BUF) + d1);               \
    gload_lds16(vp0, SMEM + vbi + 4096 * (BUF) + d0);               \
    gload_lds16(vp1, SMEM + vbi + 4096 * (BUF) + d1);               \
    kp0 += 4096; kp1 += 4096; vp0 += 64; vp1 += 64;                 \
  }
#define COMPUTE(BUF)                                                          \
  {                                                                           \
    f32x16 s0 = {};                                                           \
    __builtin_amdgcn_s_setprio(1);                                            \
    s0 = __builtin_amdgcn_mfma_f32_32x32x16_f16(                              \
        *(const f16x8*)(SMEM + kbi + 4096 * (BUF) + krA), qf[0], s0, 0, 0, 0);\
    s0 = __builtin_amdgcn_mfma_f32_32x32x16_f16(                              \
        *(const f16x8*)(SMEM + kbi + 4096 * (BUF) + krB), qf[1], s0, 0, 0, 0);\
    s0 = __builtin_amdgcn_mfma_f32_32x32x16_f16(                              \
        *(const f16x8*)(SMEM + kbi + 4096 * (BUF) + krC), qf[2], s0, 0, 0, 0);\
    s0 = __builtin_amdgcn_mfma_f32_32x32x16_f16(                              \
        *(const f16x8*)(SMEM + kbi + 4096 * (BUF) + krD), qf[3], s0, 0, 0, 0);\
    __builtin_amdgcn_s_setprio(0);                                            \
    _Pragma("unroll") for (int r = 0; r < 16; ++r) s0[r] = exp2f(s0[r]);      \
    f16x8 pa0 = mkpa(s0[0], s0[1], s0[2], s0[3], s0[4], s0[5], s0[6], s0[7]); \
    f16x8 pa1 =                                                               \
        mkpa(s0[8], s0[9], s0[10], s0[11], s0[12], s0[13], s0[14], s0[15]);   \
    __builtin_amdgcn_s_setprio(1);                                            \
    lD = __builtin_amdgcn_mfma_f32_32x32x16_f16(pa0, onesf, lD, 0, 0, 0);     \
    lD = __builtin_amdgcn_mfma_f32_32x32x16_f16(pa1, onesf, lD, 0, 0, 0);     \
    o0 = __builtin_amdgcn_mfma_f32_32x32x16_f16(                              \
        pa0, *(const f16x8*)(SMEM + vbi + 4096 * (BUF) + vA), o0, 0, 0, 0);   \
    o0 = __builtin_amdgcn_mfma_f32_32x32x16_f16(                              \
        pa1, *(const f16x8*)(SMEM + vbi + 4096 * (BUF) + vB), o0, 0, 0, 0);   \
    o1 = __builtin_amdgcn_mfma_f32_32x32x16_f16(                              \
        pa0, *(const f16x8*)(SMEM + vbi + 4096 * (BUF) + vC), o1, 0, 0, 0);   \
    o1 = __builtin_amdgcn_mfma_f32_32x32x16_f16(                              \
        pa1, *(const f16x8*)(SMEM + vbi + 4096 * (BUF) + vD), o1, 0, 0, 0);   \
    __builtin_amdgcn_s_setprio(0);                                            \
  }
#define WB12() asm volatile("s_waitcnt vmcnt(12)\ns_barrier" ::: "memory")
#define WB8()  asm volatile("s_waitcnt vmcnt(8)\ns_barrier" ::: "memory")
#define WB4()  asm volatile("s_waitcnt vmcnt(4)\ns_barrier" ::: "memory")
#define WB0()  asm volatile("s_waitcnt vmcnt(0)\ns_barrier" ::: "memory")
#define EB()   asm volatile("s_waitcnt lgkmcnt(0)\ns_barrier" ::: "memory")

  // prologue: 4 tiles in flight
  PREF(0); PREF(1); PREF(2); PREF(3);

  for (int i4 = 0; i4 < 7; ++i4) {  // tiles 0..27, prefetch 4..31
    WB12(); COMPUTE(0); EB(); PREF(0);
    WB12(); COMPUTE(1); EB(); PREF(1);
    WB12(); COMPUTE(2); EB(); PREF(2);
    WB12(); COMPUTE(3); EB(); PREF(3);
  }
  // tail: tiles 28..31 (no more prefetch)
  WB12(); COMPUTE(0); EB();
  WB8();  COMPUTE(1); EB();
  WB4();  COMPUTE(2); EB();
  WB0();  COMPUTE(3);
#undef PREF
#undef COMPUTE
#undef WB12
#undef WB8
#undef WB4
#undef WB0
#undef EB
  __syncthreads();  // all compute done before SMEM reuse below

  // ---- cross-half reduction (K/V buffers dead) ----
  float* R = (float*)SMEM;
  const int rbase = qg * 2176;
  if (hf == 1) {
#pragma unroll
    for (int rb = 0; rb < 4; ++rb) {
      f32x4 t0 = {o0[4 * rb], o0[4 * rb + 1], o0[4 * rb + 2], o0[4 * rb + 3]};
      *(f32x4*)(R + rbase + rb * 256 + lane * 4) = t0;
      f32x4 t1 = {o1[4 * rb], o1[4 * rb + 1], o1[4 * rb + 2], o1[4 * rb + 3]};
      *(f32x4*)(R + rbase + 1024 + rb * 256 + lane * 4) = t1;
    }
    if (l31 == 0) {
#pragma unroll
      for (int r = 0; r < 16; ++r)
        R[rbase + 2048 + ((r & 3) + 8 * (r >> 2) + 4 * hi)] = lD[r];
    }
  }
  __syncthreads();
  if (hf == 0) {
#pragma unroll
    for (int rb = 0; rb < 4; ++rb) {
      f32x4 t0 = *(const f32x4*)(R + rbase + rb * 256 + lane * 4);
      f32x4 t1 = *(const f32x4*)(R + rbase + 1024 + rb * 256 + lane * 4);
#pragma unroll
      for (int q = 0; q < 4; ++q) {
        o0[4 * rb + q] += t0[q];
        o1[4 * rb + q] += t1[q];
      }
    }
    const float cb = cnt[b];
#pragma unroll
    for (int r = 0; r < 16; ++r) {
      int qloc = (r & 3) + 8 * (r >> 2) + 4 * hi;
      float lq = lD[r] + R[rbase + 2048 + qloc] - cb;
      float inv = 1.0f / lq;
      int qgrow = qt * 64 + qg * 32 + qloc;
      size_t ob = ((size_t)(b * TT + qgrow) << 9) + hd * 64;
      att[ob + l31] = (f16)(o0[r] * inv);
      att[ob + 32 + l31] = (f16)(o1[r] * inv);
    }
  }
}

// ---------------- output projection: out = att @ Wo^T + bo (f32) ----------
__global__ __launch_bounds__(256) void gemm_out(const f16* __restrict__ A,
                                                const f16* __restrict__ W,
                                                const float* __restrict__ bias,
                                                float* __restrict__ out) {
  __shared__ __align__(16) f16 Alds[64 * 64];
  __shared__ __align__(16) f16 Blds[128 * 64];

  const int nt = blockIdx.x & 3;
  const int mt = blockIdx.x >> 2;
  const int tid = threadIdx.x;
  const int w = tid >> 6, lane = tid & 63;
  const int l15 = lane & 15, lg = lane >> 4;
  const int wm = w >> 1, wn = w & 1;

  f32x4 acc[2][4];
#pragma unroll
  for (int mi = 0; mi < 2; ++mi)
#pragma unroll
    for (int nj = 0; nj < 4; ++nj) acc[mi][nj] = {};

  for (int kt = 0; kt < 8; ++kt) {
#pragma unroll
    for (int i = 0; i < 2; ++i) {
      int g = (i * 4 + w) * 64 + lane;
      int row = g >> 3, jj = g & 7;
      int kb = kt * 128 + ((jj ^ (row & 7)) << 4);
      gload_lds16((const char*)A + (size_t)(mt * 64 + row) * 1024 + kb,
                  (char*)Alds + g * 16);
    }
#pragma unroll
    for (int i = 0; i < 4; ++i) {
      int g = (i * 4 + w) * 64 + lane;
      int row = g >> 3, jj = g & 7;
      int kb = kt * 128 + ((jj ^ (row & 7)) << 4);
      gload_lds16((const char*)W + (size_t)(nt * 128 + row) * 1024 + kb,
                  (char*)Blds + g * 16);
    }
    __syncthreads();

#pragma unroll
    for (int h2 = 0; h2 < 2; ++h2) {
      f16x8 af[2], bf[4];
#pragma unroll
      for (int mi = 0; mi < 2; ++mi) {
        int row = wm * 32 + mi * 16 + l15;
        int bo = (h2 * 64 + (lg << 4)) ^ ((row & 7) << 4);
        af[mi] = *(const f16x8*)((const char*)Alds + row * 128 + bo);
      }
#pragma unroll
      for (int nj = 0; nj < 4; ++nj) {
        int row = wn * 64 + nj * 16 + l15;
        int bo = (h2 * 64 + (lg << 4)) ^ ((row & 7) << 4);
        bf[nj] = *(const f16x8*)((const char*)Blds + row * 128 + bo);
      }
#pragma unroll
      for (int mi = 0; mi < 2; ++mi)
#pragma unroll
        for (int nj = 0; nj < 4; ++nj)
          acc[mi][nj] = __builtin_amdgcn_mfma_f32_16x16x32_f16(
              af[mi], bf[nj], acc[mi][nj], 0, 0, 0);
    }
    __syncthreads();
  }

  const int base_m = mt * 64 + wm * 32;
  const int base_n = nt * 128 + wn * 64;
#pragma unroll
  for (int mi = 0; mi < 2; ++mi)
#pragma unroll
    for (int nj = 0; nj < 4; ++nj) {
      int n = base_n + nj * 16 + l15;
      float bv = bias[n];
#pragma unroll
      for (int r = 0; r < 4; ++r) {
        int m = base_m + mi * 16 + (lg << 2) + r;
        out[(size_t)m * 512 + n] = acc[mi][nj][r] + bv;
      }
    }
}

// ---------------- host launch ----------------
extern "C" void kernel_launch(void* const* d_in, const int* in_sizes, int n_in,
                              void* d_out, int out_size, void* d_ws, size_t ws_size,
                              hipStream_t stream) {
  (void)in_sizes; (void)n_in; (void)out_size; (void)ws_size;
  const float* q = (const float*)d_in[0];
  const float* k = (const float*)d_in[1];
  const float* v = (const float*)d_in[2];
  const int* mask = (const int*)d_in[3];
  const float* Wq = (const float*)d_in[4];
  const float* bq = (const float*)d_in[5];
  const float* Wk = (const float*)d_in[6];
  const float* bk = (const float*)d_in[7];
  const float* Wv = (const float*)d_in[8];
  const float* bv = (const float*)d_in[9];
  const float* Wo = (const float*)d_in[10];
  const float* bo = (const float*)d_in[11];

  char* ws = (char*)d_ws;
  const size_t SZ = (size_t)8192 * 512 * 2;
  f16* q16 = (f16*)(ws + 0 * SZ);
  f16* k16 = (f16*)(ws + 1 * SZ);
  f16* v16 = (f16*)(ws + 2 * SZ);
  f16* qhp = (f16*)(ws + 3 * SZ);
  f16* khp = (f16*)(ws + 4 * SZ);
  f16* vhT = (f16*)(ws + 5 * SZ);
  f16* w16 = (f16*)(ws + 6 * SZ);
  f16* wq16 = w16;
  f16* wk16 = w16 + 262144;
  f16* wv16 = w16 + 2 * 262144;
  f16* wo16 = w16 + 3 * 262144;
  float* cntb = (float*)(ws + 6 * SZ + 4 * 262144 * sizeof(f16));
  f16* att = (f16*)(ws + 0 * SZ);

  prep<<<13316, 256, 0, stream>>>(q, k, v, Wq, Wk, Wv, Wo, mask, q16, w16, cntb);

  const float scale = 0.044194173824159216f * 1.4426950408889634f;
  gemm_qkv<<<1536, 128, 0, stream>>>(q16, k16, v16, wq16, wk16, wv16, bq, bk, bv,
                                     mask, qhp, khp, vhT, scale);

  attn_k<<<1024, 256, 0, stream>>>(qhp, khp, vhT, cntb, att);

  gemm_out<<<512, 256, 0, stream>>>(att, wo16, bo, (float*)d_out);
}